// Round 13
// baseline (170.931 us; speedup 1.0000x reference)
//
#include <hip/hip_runtime.h>

// CausalSelfAttention: B=4, T=2048, C=1024, H=16, D=64
// Pipeline: cvt(x,w) -> qkv GEMM (BK=64 dbuf, XCD chunk + 8x8 L2 supertile, swizzled LDS,
//           V written transposed) -> flash attn (swapped 32x32, KVBLK=64, fixed-shift softmax,
//           l-via-MFMA, SPLIT-KV for qt>=8 with pure-add merge) -> merge -> proj GEMM

typedef unsigned short u16b;
typedef __bf16 bf16x8 __attribute__((ext_vector_type(8)));
typedef float f32x4 __attribute__((ext_vector_type(4)));
typedef float f32x16 __attribute__((ext_vector_type(16)));
typedef unsigned short u16x4 __attribute__((ext_vector_type(4)));

#define AS1(p) ((const __attribute__((address_space(1))) void*)(p))
#define AS3(p) ((__attribute__((address_space(3))) void*)(p))
#define GLDS(g, l) __builtin_amdgcn_global_load_lds(AS1(g), AS3(l), 16, 0, 0)

__device__ __forceinline__ u16b bfr(float v) {  // f32 -> bf16 bits, RNE
  union { float f; unsigned u; } x; x.f = v;
  unsigned r = x.u + 0x7fffu + ((x.u >> 16) & 1u);
  return (u16b)(r >> 16);
}

__device__ __forceinline__ unsigned pk2(float lo, float hi) {  // pack 2 f32 -> 2 bf16 in u32
  union { __bf16 h[2]; unsigned u; } t;
  t.h[0] = (__bf16)lo; t.h[1] = (__bf16)hi;
  return t.u;
}

// ---------------- x (fp32) -> bf16, vectorized ----------------
__global__ __launch_bounds__(256) void cvt_bf16_kernel(
    const float* __restrict__ src, u16b* __restrict__ dst, int n4) {
  int i = blockIdx.x * 256 + threadIdx.x;
  const int stride = gridDim.x * 256;
  for (; i < n4; i += stride) {
    const float4 v = reinterpret_cast<const float4*>(src)[i];
    u16x4 o;
    o[0] = bfr(v.x); o[1] = bfr(v.y); o[2] = bfr(v.z); o[3] = bfr(v.w);
    reinterpret_cast<u16x4*>(dst)[i] = o;
  }
}

// ---------------- weights: src[R][C] fp32 -> dst[C][R] bf16 (transpose) ----------------
__global__ __launch_bounds__(256) void transpose_cvt_kernel(
    const float* __restrict__ src, u16b* __restrict__ dst, int R, int C) {
  __shared__ u16b tile[64][72];
  const int nc = C >> 6;
  const int br = blockIdx.x / nc, bc = blockIdx.x % nc;
  const int r0 = br << 6, c0 = bc << 6;
  const int c = threadIdx.x & 63, r4 = threadIdx.x >> 6;
  #pragma unroll
  for (int i = 0; i < 16; ++i) {
    const int r = r4 + 4 * i;
    tile[r][c] = bfr(src[(size_t)(r0 + r) * C + c0 + c]);
  }
  __syncthreads();
  #pragma unroll
  for (int i = 0; i < 16; ++i) {
    const int rr = r4 + 4 * i;
    dst[(size_t)(c0 + rr) * R + r0 + c] = tile[c][rr];
  }
}

// ---------------- 128x128 tile bf16 GEMM: BK=64 dbuf + XCD/L2 remap + XOR swizzle ----------------
// (unchanged from round 10)
template <int EPI>
__global__ __launch_bounds__(256, 2) void gemm128_kernel(
    const u16b* __restrict__ A, const u16b* __restrict__ Bt,
    const float* __restrict__ bias,
    u16b* __restrict__ oQ, u16b* __restrict__ oK, u16b* __restrict__ oVt,
    float* __restrict__ oF, int M, int N, int K) {
  __shared__ u16b smem[32768];  // 64 KB: 2 buf x (As 16KB + Bs 16KB); epilogue reuses 32KB
  const int tid = threadIdx.x;
  const int wid = tid >> 6, lane = tid & 63;
  const int xcd = blockIdx.x & 7;
  const int idx = blockIdx.x >> 3;
  const int stg = idx >> 6, rr6 = idx & 63;
  const int brow = (xcd << 3) + (rr6 >> 3);
  const int bcol = (stg << 3) + (rr6 & 7);
  const int wr = (wid >> 1) << 6, wc = (wid & 1) << 6;

  f32x4 acc[4][4] = {};

  const int srow = (wid << 5) + (lane >> 3);
  const int sc = ((lane & 7) ^ (lane >> 3)) << 3;
  const u16b* Ab = A + (size_t)((brow << 7) + srow) * K + sc;
  const u16b* Bb = Bt + (size_t)((bcol << 7) + srow) * K + sc;
  const int fr = lane & 15;
  const int fq = lane >> 4;
  const int pcs0 = ((fq) ^ (fr & 7)) << 4;
  const int pcs1 = ((4 + fq) ^ (fr & 7)) << 4;
  const int nk = K >> 6;

#define STAGE(bufi, kk)                                                        \
  {                                                                            \
    char* sb = (char*)smem + (bufi) * 32768;                                   \
    _Pragma("unroll")                                                          \
    for (int j = 0; j < 4; ++j)                                                \
      GLDS(Ab + (size_t)8 * K * j + (kk), sb + wid * 4096 + j * 1024);         \
    _Pragma("unroll")                                                          \
    for (int j = 0; j < 4; ++j)                                                \
      GLDS(Bb + (size_t)8 * K * j + (kk), sb + 16384 + wid * 4096 + j * 1024); \
  }

  STAGE(0, 0);
  STAGE(1, 64);

  #pragma unroll 1
  for (int kt = 0; kt < nk; ++kt) {
    if (kt + 1 < nk) asm volatile("s_waitcnt vmcnt(8)" ::: "memory");
    else             asm volatile("s_waitcnt vmcnt(0)" ::: "memory");
    __builtin_amdgcn_s_barrier();

    const char* As = (const char*)smem + (kt & 1) * 32768;
    const char* Bs = As + 16384;
    bf16x8 af0[4], af1[4], bf0[4], bf1[4];
    #pragma unroll
    for (int i = 0; i < 4; ++i) {
      const int rowb = (wr + i * 16 + fr) * 128;
      af0[i] = *(const bf16x8*)(As + rowb + pcs0);
      af1[i] = *(const bf16x8*)(As + rowb + pcs1);
    }
    #pragma unroll
    for (int j = 0; j < 4; ++j) {
      const int rowb = (wc + j * 16 + fr) * 128;
      bf0[j] = *(const bf16x8*)(Bs + rowb + pcs0);
      bf1[j] = *(const bf16x8*)(Bs + rowb + pcs1);
    }
    __builtin_amdgcn_s_setprio(1);
    #pragma unroll
    for (int i = 0; i < 4; ++i)
      #pragma unroll
      for (int j = 0; j < 4; ++j)
        acc[i][j] = __builtin_amdgcn_mfma_f32_16x16x32_bf16(af0[i], bf0[j], acc[i][j], 0, 0, 0);
    #pragma unroll
    for (int i = 0; i < 4; ++i)
      #pragma unroll
      for (int j = 0; j < 4; ++j)
        acc[i][j] = __builtin_amdgcn_mfma_f32_16x16x32_bf16(af1[i], bf1[j], acc[i][j], 0, 0, 0);
    __builtin_amdgcn_s_setprio(0);

    __builtin_amdgcn_s_barrier();
    if (kt + 2 < nk) STAGE(kt & 1, (kt + 2) << 6);
  }
#undef STAGE

  if (EPI == 1) {
    #pragma unroll
    for (int j = 0; j < 4; ++j) {
      const int n0 = (bcol << 7) + wc + j * 16 + fr;
      const float bv = bias[n0];
      #pragma unroll
      for (int i = 0; i < 4; ++i) {
        #pragma unroll
        for (int r = 0; r < 4; ++r) {
          const int m0 = (brow << 7) + wr + i * 16 + fq * 4 + r;
          oF[(size_t)m0 * N + n0] = acc[i][j][r] + bv;
        }
      }
    }
  } else {
    const int sect = bcol >> 3;  // 0:Q 1:K 2:V (block-uniform)
    if (sect < 2) {
      const float qs = (sect == 0) ? 0.1803368801f : 1.0f;  // 1/sqrt(64)*log2(e) in Q
      u16b* oPtr = (sect == 0) ? oQ : oK;
      u16b* tile = (u16b*)smem;
      #pragma unroll
      for (int j = 0; j < 4; ++j) {
        const int n = wc + j * 16 + fr;
        const float bv = bias[(bcol << 7) + n];
        #pragma unroll
        for (int i = 0; i < 4; ++i) {
          #pragma unroll
          for (int r = 0; r < 4; ++r) {
            const int m = wr + i * 16 + fq * 4 + r;
            const int byteoff = m * 256 + (((n >> 3) ^ (m & 7)) << 4) + ((n & 7) << 1);
            *(u16b*)((char*)tile + byteoff) = bfr((acc[i][j][r] + bv) * qs);
          }
        }
      }
      __syncthreads();
      const int nh = wid >> 1;
      const int c = lane & 7;
      #pragma unroll
      for (int it = 0; it < 8; ++it) {
        const int m = ((wid & 1) << 6) + (it << 3) + (lane >> 3);
        const int chunk = (nh << 3) + (c ^ (m & 7));
        const bf16x8 val = *(const bf16x8*)((const char*)tile + m * 256 + chunk * 16);
        const int m0 = (brow << 7) + m;
        const int n0 = (bcol << 7) + (nh << 6) + (c << 3);
        const int bb = m0 >> 11, tt = m0 & 2047;
        const int h = (n0 >> 6) & 15, d = n0 & 63;
        *(bf16x8*)(oPtr + (((size_t)(bb * 16 + h) * 2048 + tt) * 64 + d)) = val;
      }
    } else {
      // V: LDS tile TRANSPOSED [nl 128][m 128] swizzled, store Vt[bh][d][t] rows
      u16b* tile = (u16b*)smem;
      #pragma unroll
      for (int j = 0; j < 4; ++j) {
        const int nl = wc + j * 16 + fr;
        const float bv = bias[(bcol << 7) + nl];
        #pragma unroll
        for (int i = 0; i < 4; ++i) {
          #pragma unroll
          for (int r = 0; r < 4; ++r) {
            const int m = wr + i * 16 + fq * 4 + r;
            const int byteoff = nl * 256 + (((m >> 3) ^ (nl & 7)) << 4) + ((m & 7) << 1);
            *(u16b*)((char*)tile + byteoff) = bfr(acc[i][j][r] + bv);
          }
        }
      }
      __syncthreads();
      const int row0 = wid << 5;
      const int c16 = lane & 15;
      const int rw = lane >> 4;
      const int t0 = (brow << 7) & 2047;
      const int bb = brow >> 4;
      #pragma unroll
      for (int it = 0; it < 8; ++it) {
        const int nl = row0 + (it << 2) + rw;
        const int pch = c16 ^ (nl & 7);
        const bf16x8 val = *(const bf16x8*)((const char*)tile + nl * 256 + pch * 16);
        const int h = ((bcol & 7) << 1) + (nl >> 6);
        const int d = nl & 63;
        *(bf16x8*)(oVt + ((size_t)((bb << 4) + h) * 64 + d) * 2048 + t0 + (c16 << 3)) = val;
      }
    }
  }
}

// ---------------- flash attention: swapped 32x32, KVBLK=64, fixed-shift, SPLIT-KV ----------------
// Fixed-shift softmax makes split-kv merging PURE ADDITION (no max coupling):
// O = sum O_seg, l = sum l_seg. qt 8..15 (18..32 kv-iters) split into two halves of
// qt+1 iters each, writing bf16 O-partials + f32 l-partials; qt 0..7 run whole and write
// attn directly. 24 slots x 64 bh = 1536 blocks (heavy/light interleaved, 6/CU -> refill).
// Critical path drops 32 -> 16 kv-iters.
__global__ __launch_bounds__(256, 4) void flash_kernel(
    const u16b* __restrict__ Q, const u16b* __restrict__ K,
    const u16b* __restrict__ Vt, u16b* __restrict__ O,
    u16b* __restrict__ psum, float* __restrict__ lsum) {
  __shared__ u16b smem[16384];  // 32KB
  const int bid = blockIdx.x;
  const int bh = bid & 63;
  const int slot = bid >> 6;  // 0..23
  // slot -> (qt, half, split): 16 heavy halves (qt 15..8) interleaved with 8 lights (qt 7..0)
  const int m3 = slot % 3, d3 = slot / 3;
  int qt, half, split;
  if (m3 < 2) { const int hI = d3 * 2 + m3; qt = 15 - (hI >> 1); half = hI & 1; split = 1; }
  else        { qt = 7 - d3; half = 0; split = 0; }
  const int ktBeg = split ? half * (qt + 1) : 0;
  const int ktEnd = split ? (ktBeg + qt + 1) : (2 * qt + 2);

  const int tid = threadIdx.x, wid = tid >> 6, lane = tid & 63;
  const int ln31 = lane & 31, hi = lane >> 5;
  const size_t baseQK = (size_t)bh * 2048 * 64;
  const size_t baseV = (size_t)bh * 64 * 2048;
  const int b = bh >> 4, h = bh & 15;
  const int srow = wid * 8 + (lane >> 3);
  const int sc = ((lane & 7) ^ (srow & 7)) << 3;

  const int q0w = (qt << 7) + wid * 32;
  const int LT = q0w >> 6;  // last (diag) kv tile for this wave

#define FSTAGE(kt, bi)                                                         \
  {                                                                            \
    char* kb_ = (char*)smem + (bi) * 16384;                                    \
    const int k0_ = (kt) << 6;                                                 \
    GLDS(K + baseQK + (size_t)(k0_ + srow) * 64 + sc,        kb_ + wid * 1024);\
    GLDS(K + baseQK + (size_t)(k0_ + 32 + srow) * 64 + sc,   kb_ + 4096 + wid * 1024);\
    GLDS(Vt + baseV + (size_t)srow * 2048 + k0_ + sc,        kb_ + 8192 + wid * 1024);\
    GLDS(Vt + baseV + (size_t)(32 + srow) * 2048 + k0_ + sc, kb_ + 12288 + wid * 1024);\
  }

  bf16x8 qf[4];
  {
    const u16b* qp = Q + baseQK + (size_t)(q0w + ln31) * 64 + hi * 8;
    #pragma unroll
    for (int kk = 0; kk < 4; ++kk) qf[kk] = *(const bf16x8*)(qp + kk * 16);
  }
  bf16x8 ones;
  {
    union { u16b s[8]; bf16x8 v; } o1;
    #pragma unroll
    for (int i = 0; i < 8; ++i) o1.s[i] = 0x3F80;  // bf16 1.0
    ones = o1.v;
  }

  f32x16 oa0 = {}, oa1 = {}, lacc = {};

  FSTAGE(ktBeg, ktBeg & 1);
  FSTAGE(ktBeg + 1, (ktBeg + 1) & 1);  // range length always >= 2

  #pragma unroll 1
  for (int kt = ktBeg; kt < ktEnd; ++kt) {
    if (kt + 1 < ktEnd) asm volatile("s_waitcnt vmcnt(4)" ::: "memory");
    else                asm volatile("s_waitcnt vmcnt(0)" ::: "memory");
    __builtin_amdgcn_s_barrier();

    if (kt <= LT) {
      const char* kb = (const char*)smem + (kt & 1) * 16384;
      const char* vb = kb + 8192;
      const bool diag = (kt == LT);
      const int maxsub = diag ? (wid & 1) : 1;  // wave-uniform

      // ---- QK^T (swapped): s[ss] = S^T[kv=32ss+crow][q=ln31], log2 domain ----
      f32x16 s[2] = {};
      __builtin_amdgcn_s_setprio(1);
      #pragma unroll
      for (int ss = 0; ss < 2; ++ss) {
        if (ss <= maxsub) {
          const int row = 32 * ss + ln31;
          #pragma unroll
          for (int kk = 0; kk < 4; ++kk) {
            const int ch = (2 * kk + hi) ^ (row & 7);
            const bf16x8 kf = *(const bf16x8*)(kb + row * 128 + ch * 16);
            s[ss] = __builtin_amdgcn_mfma_f32_32x32x16_bf16(kf, qf[kk], s[ss], 0, 0, 0);
          }
        }
      }
      __builtin_amdgcn_s_setprio(0);

      // ---- causal mask: diag subtile is ss == (wid&1) ----
      if (diag) {
        #pragma unroll
        for (int ss = 0; ss < 2; ++ss) {
          if (ss == (wid & 1)) {
            #pragma unroll
            for (int r = 0; r < 16; ++r) {
              const int kvr = (r & 3) + 8 * (r >> 2) + 4 * hi;
              if (kvr > ln31) s[ss][r] = -3e38f;
            }
          }
        }
      }

      // ---- fixed-shift softmax: P = 2^S directly ----
      #pragma unroll
      for (int ss = 0; ss < 2; ++ss) {
        if (ss <= maxsub) {
          #pragma unroll
          for (int r = 0; r < 16; ++r)
            s[ss][r] = __builtin_amdgcn_exp2f(s[ss][r]);
        }
      }

      // ---- pack (T12) + PV + l-accumulate per subtile ----
      union WB { unsigned u[4]; bf16x8 v; };
      __builtin_amdgcn_s_setprio(1);
      #pragma unroll
      for (int ss = 0; ss < 2; ++ss) {
        if (ss <= maxsub) {
          WB pA, pB;
#define MKPA(W0, W1, W2, W3, P0, P1, P2, P3, P4, P5, P6, P7)                 \
          {                                                                   \
            unsigned a0 = pk2(P0, P1), a1 = pk2(P2, P3);                      \
            unsigned b0 = pk2(P4, P5), b1 = pk2(P6, P7);                      \
            auto r0 = __builtin_amdgcn_permlane32_swap(a0, b0, false, false); \
            auto r1 = __builtin_amdgcn_permlane32_swap(a1, b1, false, false); \
            unsigned o0[2], o1[2];                                            \
            __builtin_memcpy(o0, &r0, 8); __builtin_memcpy(o1, &r1, 8);       \
            W0 = o0[0]; W2 = o0[1]; W1 = o1[0]; W3 = o1[1];                   \
          }
          MKPA(pA.u[0], pA.u[1], pA.u[2], pA.u[3],
               s[ss][0], s[ss][1], s[ss][2], s[ss][3],
               s[ss][4], s[ss][5], s[ss][6], s[ss][7]);
          MKPA(pB.u[0], pB.u[1], pB.u[2], pB.u[3],
               s[ss][8], s[ss][9], s[ss][10], s[ss][11],
               s[ss][12], s[ss][13], s[ss][14], s[ss][15]);
#undef MKPA
          const int r0v = ln31, r1v = 32 + ln31;
          const char* v0 = vb + r0v * 128;
          const char* v1 = vb + r1v * 128;
          const int chA0 = ((4 * ss + hi) ^ (r0v & 7)) << 4;      // kv slice 2ss
          const int chA1 = ((4 * ss + hi) ^ (r1v & 7)) << 4;
          const int chB0 = ((4 * ss + 2 + hi) ^ (r0v & 7)) << 4;  // kv slice 2ss+1
          const int chB1 = ((4 * ss + 2 + hi) ^ (r1v & 7)) << 4;
          lacc = __builtin_amdgcn_mfma_f32_32x32x16_bf16(ones, pA.v, lacc, 0, 0, 0);
          oa0 = __builtin_amdgcn_mfma_f32_32x32x16_bf16(*(const bf16x8*)(v0 + chA0), pA.v, oa0, 0, 0, 0);
          oa1 = __builtin_amdgcn_mfma_f32_32x32x16_bf16(*(const bf16x8*)(v1 + chA1), pA.v, oa1, 0, 0, 0);
          lacc = __builtin_amdgcn_mfma_f32_32x32x16_bf16(ones, pB.v, lacc, 0, 0, 0);
          oa0 = __builtin_amdgcn_mfma_f32_32x32x16_bf16(*(const bf16x8*)(v0 + chB0), pB.v, oa0, 0, 0, 0);
          oa1 = __builtin_amdgcn_mfma_f32_32x32x16_bf16(*(const bf16x8*)(v1 + chB1), pB.v, oa1, 0, 0, 0);
        }
      }
      __builtin_amdgcn_s_setprio(0);
    }

    __builtin_amdgcn_s_barrier();
    if (kt + 2 < ktEnd) FSTAGE(kt + 2, kt & 1);
  }

  // ---- epilogue ----
  if (split) {
    // write bf16 O-partial (unnormalized) + f32 l-partial
    const int seg = (qt - 8) * 2 + half;
    const int row = wid * 32 + ln31;
    u16b* prow = psum + (((size_t)seg * 64 + bh) * 128 + row) * 64;
    #pragma unroll
    for (int rq = 0; rq < 4; ++rq) {
      u16x4 v0, v1;
      #pragma unroll
      for (int j = 0; j < 4; ++j) {
        v0[j] = bfr(oa0[4 * rq + j]);
        v1[j] = bfr(oa1[4 * rq + j]);
      }
      const int d0 = 8 * rq + 4 * hi;
      *(u16x4*)(prow + d0) = v0;
      *(u16x4*)(prow + 32 + d0) = v1;
    }
    if (hi == 0) lsum[seg * 8192 + bh * 128 + row] = lacc[0];
  } else {
    const float inv = 1.0f / lacc[0];
    const int q = q0w + ln31;
    u16b* orow = O + (size_t)(b * 2048 + q) * 1024 + h * 64;
    #pragma unroll
    for (int rq = 0; rq < 4; ++rq) {
      u16x4 v0, v1;
      #pragma unroll
      for (int j = 0; j < 4; ++j) {
        v0[j] = bfr(oa0[4 * rq + j] * inv);
        v1[j] = bfr(oa1[4 * rq + j] * inv);
      }
      const int d0 = 8 * rq + 4 * hi;
      *(u16x4*)(orow + d0) = v0;
      *(u16x4*)(orow + 32 + d0) = v1;
    }
  }
#undef FSTAGE
}

// ---------------- split-kv merge: attn[qt 8..15] = (O0+O1)/(l0+l1), bf16 ----------------
__global__ __launch_bounds__(256) void merge_kernel(
    const u16b* __restrict__ psum, const float* __restrict__ lsum,
    u16b* __restrict__ attn) {
  const int c = blockIdx.x * 256 + threadIdx.x;  // 524288 chunks of 8 elems
  const int dc = c & 7;
  const int row = (c >> 3) & 127;
  const int bh = (c >> 10) & 63;
  const int g = c >> 16;  // 0..7 -> qt = g + 8
  const size_t o0 = (((size_t)(g * 2) * 64 + bh) * 128 + row) * 64 + dc * 8;
  const size_t o1 = (((size_t)(g * 2 + 1) * 64 + bh) * 128 + row) * 64 + dc * 8;
  const bf16x8 a = *(const bf16x8*)(psum + o0);
  const bf16x8 bb = *(const bf16x8*)(psum + o1);
  const float l = lsum[(g * 2) * 8192 + bh * 128 + row] +
                  lsum[(g * 2 + 1) * 8192 + bh * 128 + row];
  const float inv = 1.0f / l;
  u16x4 v0, v1;
  #pragma unroll
  for (int j = 0; j < 4; ++j) {
    v0[j] = bfr(((float)a[j] + (float)bb[j]) * inv);
    v1[j] = bfr(((float)a[j + 4] + (float)bb[j + 4]) * inv);
  }
  const int q = (g + 8) * 128 + row;
  const int b = bh >> 4, hh = bh & 15;
  u16b* dst = attn + (size_t)(b * 2048 + q) * 1024 + hh * 64 + dc * 8;
  *(u16x4*)(dst) = v0;
  *(u16x4*)(dst + 4) = v1;
}

extern "C" void kernel_launch(void* const* d_in, const int* in_sizes, int n_in,
                              void* d_out, int out_size, void* d_ws, size_t ws_size,
                              hipStream_t stream) {
  const float* x      = (const float*)d_in[0];
  const float* w_attn = (const float*)d_in[1];
  const float* b_attn = (const float*)d_in[2];
  const float* w_proj = (const float*)d_in[3];
  const float* b_proj = (const float*)d_in[4];
  float* out = (float*)d_out;
  char* ws = (char*)d_ws;

  u16b* xb   = (u16b*)(ws + 0);          // [8192][1024] bf16 x; later reused as attn_out
  u16b* waT  = (u16b*)(ws + 16777216);   // [3072][1024] w_attn^T bf16 (dead after qkv GEMM)
  u16b* wpT  = (u16b*)(ws + 23068672);   // [1024][1024] w_proj^T bf16
  u16b* Qb   = (u16b*)(ws + 25165824);   // [64 bh][2048][64]
  u16b* Kb   = (u16b*)(ws + 41943040);
  u16b* psum = (u16b*)(ws + 58720256);   // [16 seg][64 bh][128 q][64 d] bf16 = 16.78 MB exact
  u16b* Vtb  = (u16b*)(ws + 75497472);   // [64 bh][64 d][2048 t] (written by qkv GEMM)
  float* lsum = (float*)(ws + 16777216); // reuse dead waT region: 16 seg x 64 x 128 f32
  u16b* attn = xb;

  cvt_bf16_kernel<<<2048, 256, 0, stream>>>(x, xb, (8192 * 1024) / 4);
  transpose_cvt_kernel<<<16 * 48, 256, 0, stream>>>(w_attn, waT, 1024, 3072);
  transpose_cvt_kernel<<<16 * 16, 256, 0, stream>>>(w_proj, wpT, 1024, 1024);
  gemm128_kernel<0><<<64 * 24, 256, 0, stream>>>(xb, waT, b_attn, Qb, Kb, Vtb, nullptr,
                                                 8192, 3072, 1024);
  flash_kernel<<<1536, 256, 0, stream>>>(Qb, Kb, Vtb, attn, psum, lsum);
  merge_kernel<<<2048, 256, 0, stream>>>(psum, lsum, attn);
  gemm128_kernel<1><<<64 * 8, 256, 0, stream>>>(attn, wpT, b_proj, nullptr, nullptr, nullptr,
                                                out, 8192, 1024, 1024);
}

// Round 14
// 166.997 us; speedup vs baseline: 1.0236x; 1.0236x over previous
//
#include <hip/hip_runtime.h>

// CausalSelfAttention: B=4, T=2048, C=1024, H=16, D=64
// Pipeline: cvt(x,w) -> qkv GEMM (256x128 tile, 8 waves, BK=32, depth-2 counted vmcnt,
//           XCD+L2 supertile, XOR-swizzled LDS, V written transposed)
//           -> flash attn (round-12: swapped 32x32, KVBLK=64, fixed-shift, l-via-MFMA)
//           -> proj GEMM (same 256x128 kernel)

typedef unsigned short u16b;
typedef __bf16 bf16x8 __attribute__((ext_vector_type(8)));
typedef float f32x4 __attribute__((ext_vector_type(4)));
typedef float f32x16 __attribute__((ext_vector_type(16)));
typedef unsigned short u16x4 __attribute__((ext_vector_type(4)));

#define AS1(p) ((const __attribute__((address_space(1))) void*)(p))
#define AS3(p) ((__attribute__((address_space(3))) void*)(p))
#define GLDS(g, l) __builtin_amdgcn_global_load_lds(AS1(g), AS3(l), 16, 0, 0)

__device__ __forceinline__ u16b bfr(float v) {  // f32 -> bf16 bits, RNE
  union { float f; unsigned u; } x; x.f = v;
  unsigned r = x.u + 0x7fffu + ((x.u >> 16) & 1u);
  return (u16b)(r >> 16);
}

__device__ __forceinline__ unsigned pk2(float lo, float hi) {  // pack 2 f32 -> 2 bf16 in u32
  union { __bf16 h[2]; unsigned u; } t;
  t.h[0] = (__bf16)lo; t.h[1] = (__bf16)hi;
  return t.u;
}

// ---------------- x (fp32) -> bf16, vectorized ----------------
__global__ __launch_bounds__(256) void cvt_bf16_kernel(
    const float* __restrict__ src, u16b* __restrict__ dst, int n4) {
  int i = blockIdx.x * 256 + threadIdx.x;
  const int stride = gridDim.x * 256;
  for (; i < n4; i += stride) {
    const float4 v = reinterpret_cast<const float4*>(src)[i];
    u16x4 o;
    o[0] = bfr(v.x); o[1] = bfr(v.y); o[2] = bfr(v.z); o[3] = bfr(v.w);
    reinterpret_cast<u16x4*>(dst)[i] = o;
  }
}

// ---------------- weights: src[R][C] fp32 -> dst[C][R] bf16 (transpose) ----------------
__global__ __launch_bounds__(256) void transpose_cvt_kernel(
    const float* __restrict__ src, u16b* __restrict__ dst, int R, int C) {
  __shared__ u16b tile[64][72];
  const int nc = C >> 6;
  const int br = blockIdx.x / nc, bc = blockIdx.x % nc;
  const int r0 = br << 6, c0 = bc << 6;
  const int c = threadIdx.x & 63, r4 = threadIdx.x >> 6;
  #pragma unroll
  for (int i = 0; i < 16; ++i) {
    const int r = r4 + 4 * i;
    tile[r][c] = bfr(src[(size_t)(r0 + r) * C + c0 + c]);
  }
  __syncthreads();
  #pragma unroll
  for (int i = 0; i < 16; ++i) {
    const int rr = r4 + 4 * i;
    dst[(size_t)(c0 + rr) * R + r0 + c] = tile[c][rr];
  }
}

// ---------------- 256x128 tile bf16 GEMM: 8 waves, BK=32, depth-2 counted vmcnt ----------------
// LDS buffers: buf b @ b*24576: A [256 rows][64 B] 16KB, B [128 rows][64 B] 8KB.
// Rows = 32 bf16 = 4 chunks of 16B; phys chunk = logical ^ (row&3) (both-sides swizzle).
// Staging: 3 GLDS/thread/K-tile (A: seg=wid*2+j covers 16 rows; B: seg=wid).
// Remap: xcd=bid&7 owns brows [xcd*4,+4); 4x4 supertile (2MB A + 1MB B in L2).
// EPI==0: Q(scaled 1/8*log2e)/K -> [B,H,T,D] bf16; V -> Vt [bh][64 d][2048 t]. EPI==1: fp32 out.
template <int EPI>
__global__ __launch_bounds__(512, 4) void gemm256_kernel(
    const u16b* __restrict__ A, const u16b* __restrict__ Bt,
    const float* __restrict__ bias,
    u16b* __restrict__ oQ, u16b* __restrict__ oK, u16b* __restrict__ oVt,
    float* __restrict__ oF, int M, int N, int K) {
  __shared__ u16b smem[32768];  // 64 KB: 2 x 24KB buffers; epilogue reuses all 64KB
  const int tid = threadIdx.x;
  const int wid = tid >> 6, lane = tid & 63;
  const int wm = wid >> 1, wn = wid & 1;
  // XCD chunk + 4x4 supertile remap (M/256 == 32, (N/128) % 4 == 0)
  const int xcd = blockIdx.x & 7;
  const int idx = blockIdx.x >> 3;
  const int bcg = idx >> 4, r16 = idx & 15;
  const int brow = (xcd << 2) + (r16 >> 2);
  const int bcol = (bcg << 2) + (r16 & 3);

  f32x4 acc[4][4] = {};

  // staging bases: col pre-swizzled (logical chunk lane&3 -> carry global chunk ^(row&3))
  const int sr = lane >> 2;                       // row within 16-row segment
  const int scol = (((lane & 3) ^ (sr & 3))) << 3;  // elems
  const u16b* Ab = A + (size_t)((brow << 8) + (wid << 5) + sr) * K + scol;
  const u16b* Bb = Bt + (size_t)((bcol << 7) + (wid << 4) + sr) * K + scol;
  const int fr = lane & 15;
  const int fq = lane >> 4;  // 0..3 = k-chunk
  const int pcs = ((fq ^ (fr & 3))) << 4;  // phys chunk byte offset for reads
  const int nk = K >> 5;

#define STAGE(t)                                                               \
  {                                                                            \
    char* sb = (char*)smem + ((t) & 1) * 24576;                                \
    GLDS(Ab + (size_t)(t) * 32,          sb + (wid * 2) * 1024);               \
    GLDS(Ab + (size_t)16 * K + (size_t)(t) * 32, sb + (wid * 2 + 1) * 1024);   \
    GLDS(Bb + (size_t)(t) * 32,          sb + 16384 + wid * 1024);             \
  }

  STAGE(0);
  STAGE(1);

  #pragma unroll 1
  for (int kt = 0; kt < nk; ++kt) {
    if (kt < nk - 1) asm volatile("s_waitcnt vmcnt(3)" ::: "memory");
    else             asm volatile("s_waitcnt vmcnt(0)" ::: "memory");
    __builtin_amdgcn_s_barrier();

    const char* As = (const char*)smem + (kt & 1) * 24576;
    const char* Bs = As + 16384;
    bf16x8 af[4], bfv[4];
    #pragma unroll
    for (int i = 0; i < 4; ++i)
      af[i] = *(const bf16x8*)(As + ((wm << 6) + i * 16 + fr) * 64 + pcs);
    #pragma unroll
    for (int j = 0; j < 4; ++j)
      bfv[j] = *(const bf16x8*)(Bs + ((wn << 6) + j * 16 + fr) * 64 + pcs);
    __builtin_amdgcn_s_setprio(1);
    #pragma unroll
    for (int i = 0; i < 4; ++i)
      #pragma unroll
      for (int j = 0; j < 4; ++j)
        acc[i][j] = __builtin_amdgcn_mfma_f32_16x16x32_bf16(af[i], bfv[j], acc[i][j], 0, 0, 0);
    __builtin_amdgcn_s_setprio(0);

    __builtin_amdgcn_s_barrier();
    if (kt + 2 < nk) STAGE(kt + 2);
  }
#undef STAGE

  if (EPI == 1) {
    #pragma unroll
    for (int j = 0; j < 4; ++j) {
      const int n0 = (bcol << 7) + (wn << 6) + j * 16 + fr;
      const float bv = bias[n0];
      #pragma unroll
      for (int i = 0; i < 4; ++i) {
        #pragma unroll
        for (int rr = 0; rr < 4; ++rr) {
          const int m0 = (brow << 8) + (wm << 6) + i * 16 + fq * 4 + rr;
          oF[(size_t)m0 * N + n0] = acc[i][j][rr] + bv;
        }
      }
    }
  } else {
    const int sect = bcol >> 3;  // 0:Q 1:K 2:V (block-uniform; 8 bcols per 1024-col section)
    if (sect < 2) {
      // LDS tile [m 256][n 128] (256B rows, 16 chunks), phys chunk = logical ^ (m&15)
      const float qs = (sect == 0) ? 0.1803368801f : 1.0f;  // 1/sqrt(64)*log2(e) in Q
      u16b* oPtr = (sect == 0) ? oQ : oK;
      char* tile = (char*)smem;
      #pragma unroll
      for (int j = 0; j < 4; ++j) {
        const int n = (wn << 6) + j * 16 + fr;
        const float bv = bias[(bcol << 7) + n];
        #pragma unroll
        for (int i = 0; i < 4; ++i) {
          #pragma unroll
          for (int rr = 0; rr < 4; ++rr) {
            const int m = (wm << 6) + i * 16 + fq * 4 + rr;
            const int byteoff = m * 256 + (((n >> 3) ^ (m & 15)) << 4) + ((n & 7) << 1);
            *(u16b*)(tile + byteoff) = bfr((acc[i][j][rr] + bv) * qs);
          }
        }
      }
      __syncthreads();
      const int c8 = tid & 15;
      #pragma unroll
      for (int rd = 0; rd < 8; ++rd) {
        const int m = rd * 32 + (tid >> 4);
        const bf16x8 val = *(const bf16x8*)(tile + m * 256 + ((c8 ^ (m & 15)) << 4));
        const int m0 = (brow << 8) + m;
        const int tt = m0 & 2047, bb = m0 >> 11;
        const int h = ((bcol & 7) << 1) + (c8 >> 3);
        const int d = (c8 & 7) << 3;
        *(bf16x8*)(oPtr + (((size_t)(bb * 16 + h) * 2048 + tt) * 64 + d)) = val;
      }
    } else {
      // V transposed: LDS [n 128][m-chunk 32] (512B rows), phys = mc ^ (n&31)
      char* tile = (char*)smem;
      #pragma unroll
      for (int j = 0; j < 4; ++j) {
        const int n = (wn << 6) + j * 16 + fr;
        const float bv = bias[(bcol << 7) + n];
        #pragma unroll
        for (int i = 0; i < 4; ++i) {
          #pragma unroll
          for (int rr = 0; rr < 4; ++rr) {
            const int m = (wm << 6) + i * 16 + fq * 4 + rr;
            const int byteoff = n * 512 + (((m >> 3) ^ (n & 31)) << 4) + ((m & 7) << 1);
            *(u16b*)(tile + byteoff) = bfr(acc[i][j][rr] + bv);
          }
        }
      }
      __syncthreads();
      const int mc = tid & 31;
      const int t0 = (brow & 7) << 8;
      const int bb = brow >> 3;
      #pragma unroll
      for (int rd = 0; rd < 8; ++rd) {
        const int n = rd * 16 + (tid >> 5);
        const bf16x8 val = *(const bf16x8*)(tile + n * 512 + ((mc ^ (n & 31)) << 4));
        const int h = ((bcol & 7) << 1) + (n >> 6);
        const int d = n & 63;
        *(bf16x8*)(oVt + ((size_t)((bb << 4) + h) * 64 + d) * 2048 + t0 + (mc << 3)) = val;
      }
    }
  }
}

// ---------------- flash attention (round-12): swapped 32x32, KVBLK=64, fixed-shift ----------------
__global__ __launch_bounds__(256, 4) void flash_kernel(
    const u16b* __restrict__ Q, const u16b* __restrict__ K,
    const u16b* __restrict__ Vt, u16b* __restrict__ O) {
  __shared__ u16b smem[16384];  // 32KB
  const int bid = blockIdx.x;
  const int bh = bid & 63;
  const int slot = bid >> 6;
  const int sg = slot & 3, sp = slot >> 2;
  const int qt = (sp & 1) ? (2 * sg + (sp >> 1)) : (15 - (sp >> 1) - 2 * sg);
  const int tid = threadIdx.x, wid = tid >> 6, lane = tid & 63;
  const int ln31 = lane & 31, hi = lane >> 5;
  const size_t baseQK = (size_t)bh * 2048 * 64;
  const size_t baseV = (size_t)bh * 64 * 2048;
  const int b = bh >> 4, h = bh & 15;
  const int srow = wid * 8 + (lane >> 3);
  const int sc = ((lane & 7) ^ (srow & 7)) << 3;

  const int q0w = (qt << 7) + wid * 32;
  const int NT = 2 * qt + 2;
  const int LT = q0w >> 6;

#define FSTAGE(kt, bi)                                                         \
  {                                                                            \
    char* kb_ = (char*)smem + (bi) * 16384;                                    \
    const int k0_ = (kt) << 6;                                                 \
    GLDS(K + baseQK + (size_t)(k0_ + srow) * 64 + sc,        kb_ + wid * 1024);\
    GLDS(K + baseQK + (size_t)(k0_ + 32 + srow) * 64 + sc,   kb_ + 4096 + wid * 1024);\
    GLDS(Vt + baseV + (size_t)srow * 2048 + k0_ + sc,        kb_ + 8192 + wid * 1024);\
    GLDS(Vt + baseV + (size_t)(32 + srow) * 2048 + k0_ + sc, kb_ + 12288 + wid * 1024);\
  }

  bf16x8 qf[4];
  {
    const u16b* qp = Q + baseQK + (size_t)(q0w + ln31) * 64 + hi * 8;
    #pragma unroll
    for (int kk = 0; kk < 4; ++kk) qf[kk] = *(const bf16x8*)(qp + kk * 16);
  }
  bf16x8 ones;
  {
    union { u16b s[8]; bf16x8 v; } o1;
    #pragma unroll
    for (int i = 0; i < 8; ++i) o1.s[i] = 0x3F80;  // bf16 1.0
    ones = o1.v;
  }

  f32x16 oa0 = {}, oa1 = {}, lacc = {};

  FSTAGE(0, 0);
  FSTAGE(1, 1);

  #pragma unroll 1
  for (int kt = 0; kt < NT; ++kt) {
    if (kt + 1 < NT) asm volatile("s_waitcnt vmcnt(4)" ::: "memory");
    else             asm volatile("s_waitcnt vmcnt(0)" ::: "memory");
    __builtin_amdgcn_s_barrier();

    if (kt <= LT) {
      const char* kb = (const char*)smem + (kt & 1) * 16384;
      const char* vb = kb + 8192;
      const bool diag = (kt == LT);
      const int maxsub = diag ? (wid & 1) : 1;  // wave-uniform

      f32x16 s[2] = {};
      __builtin_amdgcn_s_setprio(1);
      #pragma unroll
      for (int ss = 0; ss < 2; ++ss) {
        if (ss <= maxsub) {
          const int row = 32 * ss + ln31;
          #pragma unroll
          for (int kk = 0; kk < 4; ++kk) {
            const int ch = (2 * kk + hi) ^ (row & 7);
            const bf16x8 kf = *(const bf16x8*)(kb + row * 128 + ch * 16);
            s[ss] = __builtin_amdgcn_mfma_f32_32x32x16_bf16(kf, qf[kk], s[ss], 0, 0, 0);
          }
        }
      }
      __builtin_amdgcn_s_setprio(0);

      if (diag) {
        #pragma unroll
        for (int ss = 0; ss < 2; ++ss) {
          if (ss == (wid & 1)) {
            #pragma unroll
            for (int r = 0; r < 16; ++r) {
              const int kvr = (r & 3) + 8 * (r >> 2) + 4 * hi;
              if (kvr > ln31) s[ss][r] = -3e38f;
            }
          }
        }
      }

      #pragma unroll
      for (int ss = 0; ss < 2; ++ss) {
        if (ss <= maxsub) {
          #pragma unroll
          for (int r = 0; r < 16; ++r)
            s[ss][r] = __builtin_amdgcn_exp2f(s[ss][r]);
        }
      }

      union WB { unsigned u[4]; bf16x8 v; };
      __builtin_amdgcn_s_setprio(1);
      #pragma unroll
      for (int ss = 0; ss < 2; ++ss) {
        if (ss <= maxsub) {
          WB pA, pB;
#define MKPA(W0, W1, W2, W3, P0, P1, P2, P3, P4, P5, P6, P7)                 \
          {                                                                   \
            unsigned a0 = pk2(P0, P1), a1 = pk2(P2, P3);                      \
            unsigned b0 = pk2(P4, P5), b1 = pk2(P6, P7);                      \
            auto r0 = __builtin_amdgcn_permlane32_swap(a0, b0, false, false); \
            auto r1 = __builtin_amdgcn_permlane32_swap(a1, b1, false, false); \
            unsigned o0[2], o1[2];                                            \
            __builtin_memcpy(o0, &r0, 8); __builtin_memcpy(o1, &r1, 8);       \
            W0 = o0[0]; W2 = o0[1]; W1 = o1[0]; W3 = o1[1];                   \
          }
          MKPA(pA.u[0], pA.u[1], pA.u[2], pA.u[3],
               s[ss][0], s[ss][1], s[ss][2], s[ss][3],
               s[ss][4], s[ss][5], s[ss][6], s[ss][7]);
          MKPA(pB.u[0], pB.u[1], pB.u[2], pB.u[3],
               s[ss][8], s[ss][9], s[ss][10], s[ss][11],
               s[ss][12], s[ss][13], s[ss][14], s[ss][15]);
#undef MKPA
          const int r0v = ln31, r1v = 32 + ln31;
          const char* v0 = vb + r0v * 128;
          const char* v1 = vb + r1v * 128;
          const int chA0 = ((4 * ss + hi) ^ (r0v & 7)) << 4;
          const int chA1 = ((4 * ss + hi) ^ (r1v & 7)) << 4;
          const int chB0 = ((4 * ss + 2 + hi) ^ (r0v & 7)) << 4;
          const int chB1 = ((4 * ss + 2 + hi) ^ (r1v & 7)) << 4;
          lacc = __builtin_amdgcn_mfma_f32_32x32x16_bf16(ones, pA.v, lacc, 0, 0, 0);
          oa0 = __builtin_amdgcn_mfma_f32_32x32x16_bf16(*(const bf16x8*)(v0 + chA0), pA.v, oa0, 0, 0, 0);
          oa1 = __builtin_amdgcn_mfma_f32_32x32x16_bf16(*(const bf16x8*)(v1 + chA1), pA.v, oa1, 0, 0, 0);
          lacc = __builtin_amdgcn_mfma_f32_32x32x16_bf16(ones, pB.v, lacc, 0, 0, 0);
          oa0 = __builtin_amdgcn_mfma_f32_32x32x16_bf16(*(const bf16x8*)(v0 + chB0), pB.v, oa0, 0, 0, 0);
          oa1 = __builtin_amdgcn_mfma_f32_32x32x16_bf16(*(const bf16x8*)(v1 + chB1), pB.v, oa1, 0, 0, 0);
        }
      }
      __builtin_amdgcn_s_setprio(0);
    }

    __builtin_amdgcn_s_barrier();
    if (kt + 2 < NT) FSTAGE(kt + 2, kt & 1);
  }

  const float inv = 1.0f / lacc[0];
  const int q = q0w + ln31;
  u16b* orow = O + (size_t)(b * 2048 + q) * 1024 + h * 64;
  #pragma unroll
  for (int rq = 0; rq < 4; ++rq) {
    u16x4 v0, v1;
    #pragma unroll
    for (int j = 0; j < 4; ++j) {
      v0[j] = bfr(oa0[4 * rq + j] * inv);
      v1[j] = bfr(oa1[4 * rq + j] * inv);
    }
    const int d0 = 8 * rq + 4 * hi;
    *(u16x4*)(orow + d0) = v0;
    *(u16x4*)(orow + 32 + d0) = v1;
  }
#undef FSTAGE
}

extern "C" void kernel_launch(void* const* d_in, const int* in_sizes, int n_in,
                              void* d_out, int out_size, void* d_ws, size_t ws_size,
                              hipStream_t stream) {
  const float* x      = (const float*)d_in[0];
  const float* w_attn = (const float*)d_in[1];
  const float* b_attn = (const float*)d_in[2];
  const float* w_proj = (const float*)d_in[3];
  const float* b_proj = (const float*)d_in[4];
  float* out = (float*)d_out;
  char* ws = (char*)d_ws;

  u16b* xb  = (u16b*)(ws + 0);          // [8192][1024] bf16 x; later reused as attn_out
  u16b* waT = (u16b*)(ws + 16777216);   // [3072][1024] w_attn^T bf16
  u16b* wpT = (u16b*)(ws + 23068672);   // [1024][1024] w_proj^T bf16
  u16b* Qb  = (u16b*)(ws + 25165824);   // [64 bh][2048][64]
  u16b* Kb  = (u16b*)(ws + 41943040);
  u16b* Vtb = (u16b*)(ws + 75497472);   // [64 bh][64 d][2048 t] (written by qkv GEMM)
  u16b* attn = xb;

  cvt_bf16_kernel<<<2048, 256, 0, stream>>>(x, xb, (8192 * 1024) / 4);
  transpose_cvt_kernel<<<16 * 48, 256, 0, stream>>>(w_attn, waT, 1024, 3072);
  transpose_cvt_kernel<<<16 * 16, 256, 0, stream>>>(w_proj, wpT, 1024, 1024);
  // qkv: M=8192 (32 brows), N=3072 (24 bcols) -> grid 768
  gemm256_kernel<0><<<768, 512, 0, stream>>>(xb, waT, b_attn, Qb, Kb, Vtb, nullptr,
                                             8192, 3072, 1024);
  flash_kernel<<<1024, 256, 0, stream>>>(Qb, Kb, Vtb, attn);
  // proj: M=8192, N=1024 (8 bcols) -> grid 256
  gemm256_kernel<1><<<256, 512, 0, stream>>>(attn, wpT, b_proj, nullptr, nullptr, nullptr,
                                             out, 8192, 1024, 1024);
}

// Round 15
// 150.558 us; speedup vs baseline: 1.1353x; 1.1092x over previous
//
#include <hip/hip_runtime.h>

// CausalSelfAttention: B=4, T=2048, C=1024, H=16, D=64
// Pipeline: cvt(x,w) -> qkv GEMM (round-12 gemm128: BK=64 dbuf, XCD chunk + 8x8 L2 supertile,
//           XOR-swizzled LDS, V written transposed)
//           -> flash attn (swapped 32x32, KVBLK=64, fixed-shift, l-via-MFMA,
//              3-buffer SINGLE-BARRIER pipeline) -> proj GEMM

typedef unsigned short u16b;
typedef __bf16 bf16x8 __attribute__((ext_vector_type(8)));
typedef float f32x4 __attribute__((ext_vector_type(4)));
typedef float f32x16 __attribute__((ext_vector_type(16)));
typedef unsigned short u16x4 __attribute__((ext_vector_type(4)));

#define AS1(p) ((const __attribute__((address_space(1))) void*)(p))
#define AS3(p) ((__attribute__((address_space(3))) void*)(p))
#define GLDS(g, l) __builtin_amdgcn_global_load_lds(AS1(g), AS3(l), 16, 0, 0)

__device__ __forceinline__ u16b bfr(float v) {  // f32 -> bf16 bits, RNE
  union { float f; unsigned u; } x; x.f = v;
  unsigned r = x.u + 0x7fffu + ((x.u >> 16) & 1u);
  return (u16b)(r >> 16);
}

__device__ __forceinline__ unsigned pk2(float lo, float hi) {  // pack 2 f32 -> 2 bf16 in u32
  union { __bf16 h[2]; unsigned u; } t;
  t.h[0] = (__bf16)lo; t.h[1] = (__bf16)hi;
  return t.u;
}

// ---------------- x (fp32) -> bf16, vectorized ----------------
__global__ __launch_bounds__(256) void cvt_bf16_kernel(
    const float* __restrict__ src, u16b* __restrict__ dst, int n4) {
  int i = blockIdx.x * 256 + threadIdx.x;
  const int stride = gridDim.x * 256;
  for (; i < n4; i += stride) {
    const float4 v = reinterpret_cast<const float4*>(src)[i];
    u16x4 o;
    o[0] = bfr(v.x); o[1] = bfr(v.y); o[2] = bfr(v.z); o[3] = bfr(v.w);
    reinterpret_cast<u16x4*>(dst)[i] = o;
  }
}

// ---------------- weights: src[R][C] fp32 -> dst[C][R] bf16 (transpose) ----------------
__global__ __launch_bounds__(256) void transpose_cvt_kernel(
    const float* __restrict__ src, u16b* __restrict__ dst, int R, int C) {
  __shared__ u16b tile[64][72];
  const int nc = C >> 6;
  const int br = blockIdx.x / nc, bc = blockIdx.x % nc;
  const int r0 = br << 6, c0 = bc << 6;
  const int c = threadIdx.x & 63, r4 = threadIdx.x >> 6;
  #pragma unroll
  for (int i = 0; i < 16; ++i) {
    const int r = r4 + 4 * i;
    tile[r][c] = bfr(src[(size_t)(r0 + r) * C + c0 + c]);
  }
  __syncthreads();
  #pragma unroll
  for (int i = 0; i < 16; ++i) {
    const int rr = r4 + 4 * i;
    dst[(size_t)(c0 + rr) * R + r0 + c] = tile[c][rr];
  }
}

// ---------------- 128x128 tile bf16 GEMM: BK=64 dbuf + XCD/L2 remap + XOR swizzle ----------------
// (round-12 exact — best measured GEMM config)
template <int EPI>
__global__ __launch_bounds__(256, 2) void gemm128_kernel(
    const u16b* __restrict__ A, const u16b* __restrict__ Bt,
    const float* __restrict__ bias,
    u16b* __restrict__ oQ, u16b* __restrict__ oK, u16b* __restrict__ oVt,
    float* __restrict__ oF, int M, int N, int K) {
  __shared__ u16b smem[32768];  // 64 KB: 2 buf x (As 16KB + Bs 16KB); epilogue reuses 32KB
  const int tid = threadIdx.x;
  const int wid = tid >> 6, lane = tid & 63;
  const int xcd = blockIdx.x & 7;
  const int idx = blockIdx.x >> 3;
  const int stg = idx >> 6, rr6 = idx & 63;
  const int brow = (xcd << 3) + (rr6 >> 3);
  const int bcol = (stg << 3) + (rr6 & 7);
  const int wr = (wid >> 1) << 6, wc = (wid & 1) << 6;

  f32x4 acc[4][4] = {};

  const int srow = (wid << 5) + (lane >> 3);
  const int sc = ((lane & 7) ^ (lane >> 3)) << 3;
  const u16b* Ab = A + (size_t)((brow << 7) + srow) * K + sc;
  const u16b* Bb = Bt + (size_t)((bcol << 7) + srow) * K + sc;
  const int fr = lane & 15;
  const int fq = lane >> 4;
  const int pcs0 = ((fq) ^ (fr & 7)) << 4;
  const int pcs1 = ((4 + fq) ^ (fr & 7)) << 4;
  const int nk = K >> 6;

#define STAGE(bufi, kk)                                                        \
  {                                                                            \
    char* sb = (char*)smem + (bufi) * 32768;                                   \
    _Pragma("unroll")                                                          \
    for (int j = 0; j < 4; ++j)                                                \
      GLDS(Ab + (size_t)8 * K * j + (kk), sb + wid * 4096 + j * 1024);         \
    _Pragma("unroll")                                                          \
    for (int j = 0; j < 4; ++j)                                                \
      GLDS(Bb + (size_t)8 * K * j + (kk), sb + 16384 + wid * 4096 + j * 1024); \
  }

  STAGE(0, 0);
  STAGE(1, 64);

  #pragma unroll 1
  for (int kt = 0; kt < nk; ++kt) {
    if (kt + 1 < nk) asm volatile("s_waitcnt vmcnt(8)" ::: "memory");
    else             asm volatile("s_waitcnt vmcnt(0)" ::: "memory");
    __builtin_amdgcn_s_barrier();

    const char* As = (const char*)smem + (kt & 1) * 32768;
    const char* Bs = As + 16384;
    bf16x8 af0[4], af1[4], bf0[4], bf1[4];
    #pragma unroll
    for (int i = 0; i < 4; ++i) {
      const int rowb = (wr + i * 16 + fr) * 128;
      af0[i] = *(const bf16x8*)(As + rowb + pcs0);
      af1[i] = *(const bf16x8*)(As + rowb + pcs1);
    }
    #pragma unroll
    for (int j = 0; j < 4; ++j) {
      const int rowb = (wc + j * 16 + fr) * 128;
      bf0[j] = *(const bf16x8*)(Bs + rowb + pcs0);
      bf1[j] = *(const bf16x8*)(Bs + rowb + pcs1);
    }
    __builtin_amdgcn_s_setprio(1);
    #pragma unroll
    for (int i = 0; i < 4; ++i)
      #pragma unroll
      for (int j = 0; j < 4; ++j)
        acc[i][j] = __builtin_amdgcn_mfma_f32_16x16x32_bf16(af0[i], bf0[j], acc[i][j], 0, 0, 0);
    #pragma unroll
    for (int i = 0; i < 4; ++i)
      #pragma unroll
      for (int j = 0; j < 4; ++j)
        acc[i][j] = __builtin_amdgcn_mfma_f32_16x16x32_bf16(af1[i], bf1[j], acc[i][j], 0, 0, 0);
    __builtin_amdgcn_s_setprio(0);

    __builtin_amdgcn_s_barrier();
    if (kt + 2 < nk) STAGE(kt & 1, (kt + 2) << 6);
  }
#undef STAGE

  if (EPI == 1) {
    #pragma unroll
    for (int j = 0; j < 4; ++j) {
      const int n0 = (bcol << 7) + wc + j * 16 + fr;
      const float bv = bias[n0];
      #pragma unroll
      for (int i = 0; i < 4; ++i) {
        #pragma unroll
        for (int r = 0; r < 4; ++r) {
          const int m0 = (brow << 7) + wr + i * 16 + fq * 4 + r;
          oF[(size_t)m0 * N + n0] = acc[i][j][r] + bv;
        }
      }
    }
  } else {
    const int sect = bcol >> 3;  // 0:Q 1:K 2:V (block-uniform)
    if (sect < 2) {
      const float qs = (sect == 0) ? 0.1803368801f : 1.0f;  // 1/sqrt(64)*log2(e) in Q
      u16b* oPtr = (sect == 0) ? oQ : oK;
      u16b* tile = (u16b*)smem;
      #pragma unroll
      for (int j = 0; j < 4; ++j) {
        const int n = wc + j * 16 + fr;
        const float bv = bias[(bcol << 7) + n];
        #pragma unroll
        for (int i = 0; i < 4; ++i) {
          #pragma unroll
          for (int r = 0; r < 4; ++r) {
            const int m = wr + i * 16 + fq * 4 + r;
            const int byteoff = m * 256 + (((n >> 3) ^ (m & 7)) << 4) + ((n & 7) << 1);
            *(u16b*)((char*)tile + byteoff) = bfr((acc[i][j][r] + bv) * qs);
          }
        }
      }
      __syncthreads();
      const int nh = wid >> 1;
      const int c = lane & 7;
      #pragma unroll
      for (int it = 0; it < 8; ++it) {
        const int m = ((wid & 1) << 6) + (it << 3) + (lane >> 3);
        const int chunk = (nh << 3) + (c ^ (m & 7));
        const bf16x8 val = *(const bf16x8*)((const char*)tile + m * 256 + chunk * 16);
        const int m0 = (brow << 7) + m;
        const int n0 = (bcol << 7) + (nh << 6) + (c << 3);
        const int bb = m0 >> 11, tt = m0 & 2047;
        const int h = (n0 >> 6) & 15, d = n0 & 63;
        *(bf16x8*)(oPtr + (((size_t)(bb * 16 + h) * 2048 + tt) * 64 + d)) = val;
      }
    } else {
      // V: LDS tile TRANSPOSED [nl 128][m 128] swizzled, store Vt[bh][d][t] rows
      u16b* tile = (u16b*)smem;
      #pragma unroll
      for (int j = 0; j < 4; ++j) {
        const int nl = wc + j * 16 + fr;
        const float bv = bias[(bcol << 7) + nl];
        #pragma unroll
        for (int i = 0; i < 4; ++i) {
          #pragma unroll
          for (int r = 0; r < 4; ++r) {
            const int m = wr + i * 16 + fq * 4 + r;
            const int byteoff = nl * 256 + (((m >> 3) ^ (nl & 7)) << 4) + ((m & 7) << 1);
            *(u16b*)((char*)tile + byteoff) = bfr(acc[i][j][r] + bv);
          }
        }
      }
      __syncthreads();
      const int row0 = wid << 5;
      const int c16 = lane & 15;
      const int rw = lane >> 4;
      const int t0 = (brow << 7) & 2047;
      const int bb = brow >> 4;
      #pragma unroll
      for (int it = 0; it < 8; ++it) {
        const int nl = row0 + (it << 2) + rw;
        const int pch = c16 ^ (nl & 7);
        const bf16x8 val = *(const bf16x8*)((const char*)tile + nl * 256 + pch * 16);
        const int h = ((bcol & 7) << 1) + (nl >> 6);
        const int d = nl & 63;
        *(bf16x8*)(oVt + ((size_t)((bb << 4) + h) * 64 + d) * 2048 + t0 + (c16 << 3)) = val;
      }
    }
  }
}

// ---------------- flash attention: swapped 32x32, KVBLK=64, 3-buffer SINGLE-BARRIER ----------------
// One barrier per kv-iteration (was 2). Proof of safety: stage at iter kt writes
// buf[(kt+2)%3], which holds tile kt-1 — each wave's compute(kt-1) precedes its arrival
// at barrier(kt) in program order, so after barrier(kt) no wave can still read it.
// Per-wave vmcnt(4) at iter top completes that wave's tile-kt loads; the barrier
// publishes completion across waves (same as the 2-buffer scheme). LDS 48KB -> 3 blocks/CU.
__global__ __launch_bounds__(256, 3) void flash_kernel(
    const u16b* __restrict__ Q, const u16b* __restrict__ K,
    const u16b* __restrict__ Vt, u16b* __restrict__ O) {
  __shared__ u16b smem[24576];  // 48KB: 3 x (K 8KB + V 8KB)
  const int bid = blockIdx.x;
  const int bh = bid & 63;
  const int qt = 15 - (bid >> 6);  // heavy q-tiles dispatch first
  const int tid = threadIdx.x, wid = tid >> 6, lane = tid & 63;
  const int ln31 = lane & 31, hi = lane >> 5;
  const size_t baseQK = (size_t)bh * 2048 * 64;
  const size_t baseV = (size_t)bh * 64 * 2048;
  const int b = bh >> 4, h = bh & 15;
  const int srow = wid * 8 + (lane >> 3);
  const int sc = ((lane & 7) ^ (srow & 7)) << 3;

  const int q0w = (qt << 7) + wid * 32;
  const int NT = 2 * qt + 2;
  const int LT = q0w >> 6;

#define FSTAGE(kt, bi)                                                         \
  {                                                                            \
    char* kb_ = (char*)smem + (bi) * 16384;                                    \
    const int k0_ = (kt) << 6;                                                 \
    GLDS(K + baseQK + (size_t)(k0_ + srow) * 64 + sc,        kb_ + wid * 1024);\
    GLDS(K + baseQK + (size_t)(k0_ + 32 + srow) * 64 + sc,   kb_ + 4096 + wid * 1024);\
    GLDS(Vt + baseV + (size_t)srow * 2048 + k0_ + sc,        kb_ + 8192 + wid * 1024);\
    GLDS(Vt + baseV + (size_t)(32 + srow) * 2048 + k0_ + sc, kb_ + 12288 + wid * 1024);\
  }

  bf16x8 qf[4];
  {
    const u16b* qp = Q + baseQK + (size_t)(q0w + ln31) * 64 + hi * 8;
    #pragma unroll
    for (int kk = 0; kk < 4; ++kk) qf[kk] = *(const bf16x8*)(qp + kk * 16);
  }
  bf16x8 ones;
  {
    union { u16b s[8]; bf16x8 v; } o1;
    #pragma unroll
    for (int i = 0; i < 8; ++i) o1.s[i] = 0x3F80;  // bf16 1.0
    ones = o1.v;
  }

  f32x16 oa0 = {}, oa1 = {}, lacc = {};

  FSTAGE(0, 0);
  FSTAGE(1, 1);

  int buf = 0;       // kt % 3
  int nbuf = 2;      // (kt+2) % 3
  #pragma unroll 1
  for (int kt = 0; kt < NT; ++kt) {
    if (kt + 1 < NT) asm volatile("s_waitcnt vmcnt(4)" ::: "memory");
    else             asm volatile("s_waitcnt vmcnt(0)" ::: "memory");
    __builtin_amdgcn_s_barrier();

    if (kt + 2 < NT) FSTAGE(kt + 2, nbuf);  // issue early: hides under compute

    if (kt <= LT) {
      const char* kb = (const char*)smem + buf * 16384;
      const char* vb = kb + 8192;
      const bool diag = (kt == LT);
      const int maxsub = diag ? (wid & 1) : 1;  // wave-uniform

      f32x16 s[2] = {};
      __builtin_amdgcn_s_setprio(1);
      #pragma unroll
      for (int ss = 0; ss < 2; ++ss) {
        if (ss <= maxsub) {
          const int row = 32 * ss + ln31;
          #pragma unroll
          for (int kk = 0; kk < 4; ++kk) {
            const int ch = (2 * kk + hi) ^ (row & 7);
            const bf16x8 kf = *(const bf16x8*)(kb + row * 128 + ch * 16);
            s[ss] = __builtin_amdgcn_mfma_f32_32x32x16_bf16(kf, qf[kk], s[ss], 0, 0, 0);
          }
        }
      }
      __builtin_amdgcn_s_setprio(0);

      if (diag) {
        #pragma unroll
        for (int ss = 0; ss < 2; ++ss) {
          if (ss == (wid & 1)) {
            #pragma unroll
            for (int r = 0; r < 16; ++r) {
              const int kvr = (r & 3) + 8 * (r >> 2) + 4 * hi;
              if (kvr > ln31) s[ss][r] = -3e38f;
            }
          }
        }
      }

      #pragma unroll
      for (int ss = 0; ss < 2; ++ss) {
        if (ss <= maxsub) {
          #pragma unroll
          for (int r = 0; r < 16; ++r)
            s[ss][r] = __builtin_amdgcn_exp2f(s[ss][r]);
        }
      }

      union WB { unsigned u[4]; bf16x8 v; };
      __builtin_amdgcn_s_setprio(1);
      #pragma unroll
      for (int ss = 0; ss < 2; ++ss) {
        if (ss <= maxsub) {
          WB pA, pB;
#define MKPA(W0, W1, W2, W3, P0, P1, P2, P3, P4, P5, P6, P7)                 \
          {                                                                   \
            unsigned a0 = pk2(P0, P1), a1 = pk2(P2, P3);                      \
            unsigned b0 = pk2(P4, P5), b1 = pk2(P6, P7);                      \
            auto r0 = __builtin_amdgcn_permlane32_swap(a0, b0, false, false); \
            auto r1 = __builtin_amdgcn_permlane32_swap(a1, b1, false, false); \
            unsigned o0[2], o1[2];                                            \
            __builtin_memcpy(o0, &r0, 8); __builtin_memcpy(o1, &r1, 8);       \
            W0 = o0[0]; W2 = o0[1]; W1 = o1[0]; W3 = o1[1];                   \
          }
          MKPA(pA.u[0], pA.u[1], pA.u[2], pA.u[3],
               s[ss][0], s[ss][1], s[ss][2], s[ss][3],
               s[ss][4], s[ss][5], s[ss][6], s[ss][7]);
          MKPA(pB.u[0], pB.u[1], pB.u[2], pB.u[3],
               s[ss][8], s[ss][9], s[ss][10], s[ss][11],
               s[ss][12], s[ss][13], s[ss][14], s[ss][15]);
#undef MKPA
          const int r0v = ln31, r1v = 32 + ln31;
          const char* v0 = vb + r0v * 128;
          const char* v1 = vb + r1v * 128;
          const int chA0 = ((4 * ss + hi) ^ (r0v & 7)) << 4;
          const int chA1 = ((4 * ss + hi) ^ (r1v & 7)) << 4;
          const int chB0 = ((4 * ss + 2 + hi) ^ (r0v & 7)) << 4;
          const int chB1 = ((4 * ss + 2 + hi) ^ (r1v & 7)) << 4;
          lacc = __builtin_amdgcn_mfma_f32_32x32x16_bf16(ones, pA.v, lacc, 0, 0, 0);
          oa0 = __builtin_amdgcn_mfma_f32_32x32x16_bf16(*(const bf16x8*)(v0 + chA0), pA.v, oa0, 0, 0, 0);
          oa1 = __builtin_amdgcn_mfma_f32_32x32x16_bf16(*(const bf16x8*)(v1 + chA1), pA.v, oa1, 0, 0, 0);
          lacc = __builtin_amdgcn_mfma_f32_32x32x16_bf16(ones, pB.v, lacc, 0, 0, 0);
          oa0 = __builtin_amdgcn_mfma_f32_32x32x16_bf16(*(const bf16x8*)(v0 + chB0), pB.v, oa0, 0, 0, 0);
          oa1 = __builtin_amdgcn_mfma_f32_32x32x16_bf16(*(const bf16x8*)(v1 + chB1), pB.v, oa1, 0, 0, 0);
        }
      }
      __builtin_amdgcn_s_setprio(0);
    }

    buf = (buf == 2) ? 0 : buf + 1;
    nbuf = (nbuf == 2) ? 0 : nbuf + 1;
  }

  const float inv = 1.0f / lacc[0];
  const int q = q0w + ln31;
  u16b* orow = O + (size_t)(b * 2048 + q) * 1024 + h * 64;
  #pragma unroll
  for (int rq = 0; rq < 4; ++rq) {
    u16x4 v0, v1;
    #pragma unroll
    for (int j = 0; j < 4; ++j) {
      v0[j] = bfr(oa0[4 * rq + j] * inv);
      v1[j] = bfr(oa1[4 * rq + j] * inv);
    }
    const int d0 = 8 * rq + 4 * hi;
    *(u16x4*)(orow + d0) = v0;
    *(u16x4*)(orow + 32 + d0) = v1;
  }
#undef FSTAGE
}

extern "C" void kernel_launch(void* const* d_in, const int* in_sizes, int n_in,
                              void* d_out, int out_size, void* d_ws, size_t ws_size,
                              hipStream_t stream) {
  const float* x      = (const float*)d_in[0];
  const float* w_attn = (const float*)d_in[1];
  const float* b_attn = (const float*)d_in[2];
  const float* w_proj = (const float*)d_in[3];
  const float* b_proj = (const float*)d_in[4];
  float* out = (float*)d_out;
  char* ws = (char*)d_ws;

  u16b* xb  = (u16b*)(ws + 0);          // [8192][1024] bf16 x; later reused as attn_out
  u16b* waT = (u16b*)(ws + 16777216);   // [3072][1024] w_attn^T bf16
  u16b* wpT = (u16b*)(ws + 23068672);   // [1024][1024] w_proj^T bf16
  u16b* Qb  = (u16b*)(ws + 25165824);   // [64 bh][2048][64]
  u16b* Kb  = (u16b*)(ws + 41943040);
  u16b* Vtb = (u16b*)(ws + 75497472);   // [64 bh][64 d][2048 t] (written by qkv GEMM)
  u16b* attn = xb;

  cvt_bf16_kernel<<<2048, 256, 0, stream>>>(x, xb, (8192 * 1024) / 4);
  transpose_cvt_kernel<<<16 * 48, 256, 0, stream>>>(w_attn, waT, 1024, 3072);
  transpose_cvt_kernel<<<16 * 16, 256, 0, stream>>>(w_proj, wpT, 1024, 1024);
  gemm128_kernel<0><<<64 * 24, 256, 0, stream>>>(xb, waT, b_attn, Qb, Kb, Vtb, nullptr,
                                                 8192, 3072, 1024);
  flash_kernel<<<1024, 256, 0, stream>>>(Qb, Kb, Vtb, attn);
  gemm128_kernel<1><<<64 * 8, 256, 0, stream>>>(attn, wpT, b_proj, nullptr, nullptr, nullptr,
                                                out, 8192, 1024, 1024);
}